// Round 1
// baseline (346.779 us; speedup 1.0000x reference)
//
#include <hip/hip_runtime.h>
#include <hip/hip_bf16.h>

typedef __attribute__((ext_vector_type(8))) short short8;
typedef __attribute__((ext_vector_type(4))) float f32x4;

#define LDK 328   // 320 + 8 bf16 pad -> row stride 656B = 164 dwords, 164%32=4 -> 2-way (free)

__device__ __forceinline__ unsigned short f2bf(float f) {
    unsigned int u = __float_as_uint(f);
    unsigned int r = (u + 0x7fffu + ((u >> 16) & 1u)) >> 16;   // RNE
    return (unsigned short)r;
}

__device__ __forceinline__ float4 min4(float4 a, float4 b) {
    return make_float4(fminf(a.x,b.x), fminf(a.y,b.y), fminf(a.z,b.z), fminf(a.w,b.w));
}
__device__ __forceinline__ float4 max4(float4 a, float4 b) {
    return make_float4(fmaxf(a.x,b.x), fmaxf(a.y,b.y), fmaxf(a.z,b.z), fmaxf(a.w,b.w));
}

__global__ void zero_kernel(float* __restrict__ p, int n) {
    int i = blockIdx.x * 256 + threadIdx.x;
    if (i < n) p[i] = 0.f;
}

__global__ void convert_w_kernel(const float* __restrict__ W,
                                 unsigned short* __restrict__ Wb, int n) {
    int i = blockIdx.x * 256 + threadIdx.x;
    if (i < n) Wb[i] = f2bf(W[i]);
}

// One block: 64 rows x all 128 output channels. K = 320 (5 sections of 64).
__global__ __launch_bounds__(256, 3) void fused_kernel(
    const float* __restrict__ x, const int* __restrict__ nb,
    const unsigned short* __restrict__ Wb, float* __restrict__ h,
    float* __restrict__ partials, int E)
{
    __shared__ __align__(16) unsigned short feat[64 * LDK];
    __shared__ float sstat[256];

    const int tid = threadIdx.x;
    sstat[tid] = 0.f;

    const int r0 = blockIdx.x * 64;

    // ---- stage feat tile: [x | min(n0,n1) | max(n0,n1) | min(n2,n3) | max(n2,n3)] as bf16
    #pragma unroll
    for (int t = tid; t < 64 * 16; t += 256) {
        const int lr = t >> 4;             // local row 0..63
        const int c4 = (t & 15) * 4;       // col chunk (float4) within 64
        const int gr = min(r0 + lr, E - 1);

        const float4 xv = *(const float4*)(x + gr * 64 + c4);
        int i0 = nb[gr * 4 + 0]; i0 = min(max(i0, 0), E - 1);
        int i1 = nb[gr * 4 + 1]; i1 = min(max(i1, 0), E - 1);
        int i2 = nb[gr * 4 + 2]; i2 = min(max(i2, 0), E - 1);
        int i3 = nb[gr * 4 + 3]; i3 = min(max(i3, 0), E - 1);
        const float4 a = *(const float4*)(x + i0 * 64 + c4);
        const float4 b = *(const float4*)(x + i1 * 64 + c4);
        const float4 c = *(const float4*)(x + i2 * 64 + c4);
        const float4 d = *(const float4*)(x + i3 * 64 + c4);

        const float4 vals[5] = { xv, min4(a,b), max4(a,b), min4(c,d), max4(c,d) };
        #pragma unroll
        for (int s = 0; s < 5; ++s) {
            ushort4 p;
            p.x = f2bf(vals[s].x); p.y = f2bf(vals[s].y);
            p.z = f2bf(vals[s].z); p.w = f2bf(vals[s].w);
            *(ushort4*)(&feat[lr * LDK + s * 64 + c4]) = p;
        }
    }
    __syncthreads();

    // ---- MFMA: 4 waves in 2x2 grid; each wave: 32 rows x 64 cols
    const int lane = tid & 63;
    const int wid  = tid >> 6;
    const int wm   = wid >> 1;          // 0..1 row half
    const int wn   = wid & 1;           // 0..1 col half
    const int lr16 = lane & 15;
    const int lg   = lane >> 4;         // 0..3

    f32x4 acc[2][4];
    #pragma unroll
    for (int m = 0; m < 2; ++m)
        #pragma unroll
        for (int n = 0; n < 4; ++n)
            acc[m][n] = (f32x4){0.f, 0.f, 0.f, 0.f};

    const unsigned short* fbase = &feat[(wm * 32 + lr16) * LDK + lg * 8];
    const unsigned short* wbase = Wb + (wn * 64 + lr16) * 320 + lg * 8;

    #pragma unroll
    for (int kk = 0; kk < 320; kk += 32) {
        const short8 a0 = *(const short8*)(fbase + kk);
        const short8 a1 = *(const short8*)(fbase + 16 * LDK + kk);
        const short8 b0 = *(const short8*)(wbase + kk);
        const short8 b1 = *(const short8*)(wbase + 16 * 320 + kk);
        const short8 b2 = *(const short8*)(wbase + 32 * 320 + kk);
        const short8 b3 = *(const short8*)(wbase + 48 * 320 + kk);
        acc[0][0] = __builtin_amdgcn_mfma_f32_16x16x32_bf16(a0, b0, acc[0][0], 0, 0, 0);
        acc[0][1] = __builtin_amdgcn_mfma_f32_16x16x32_bf16(a0, b1, acc[0][1], 0, 0, 0);
        acc[0][2] = __builtin_amdgcn_mfma_f32_16x16x32_bf16(a0, b2, acc[0][2], 0, 0, 0);
        acc[0][3] = __builtin_amdgcn_mfma_f32_16x16x32_bf16(a0, b3, acc[0][3], 0, 0, 0);
        acc[1][0] = __builtin_amdgcn_mfma_f32_16x16x32_bf16(a1, b0, acc[1][0], 0, 0, 0);
        acc[1][1] = __builtin_amdgcn_mfma_f32_16x16x32_bf16(a1, b1, acc[1][1], 0, 0, 0);
        acc[1][2] = __builtin_amdgcn_mfma_f32_16x16x32_bf16(a1, b2, acc[1][2], 0, 0, 0);
        acc[1][3] = __builtin_amdgcn_mfma_f32_16x16x32_bf16(a1, b3, acc[1][3], 0, 0, 0);
    }

    // ---- epilogue: write h (unnormalized) + per-channel sum/sumsq
    // D layout (measured m89/m91): col = lane&15, row = (lane>>4)*4 + reg
    #pragma unroll
    for (int n = 0; n < 4; ++n) {
        const int col = wn * 64 + n * 16 + lr16;
        float s = 0.f, q = 0.f;
        #pragma unroll
        for (int m = 0; m < 2; ++m) {
            const int rbase = r0 + wm * 32 + m * 16 + lg * 4;
            #pragma unroll
            for (int j = 0; j < 4; ++j) {
                const int grow = rbase + j;
                const float v = acc[m][n][j];
                if (grow < E) {
                    h[(long)grow * 128 + col] = v;
                    s += v;
                    q += v * v;
                }
            }
        }
        // lanes l, l^16, l^32, l^48 share this channel
        s += __shfl_xor(s, 16); s += __shfl_xor(s, 32);
        q += __shfl_xor(q, 16); q += __shfl_xor(q, 32);
        if (lg == 0) {
            atomicAdd(&sstat[col], s);
            atomicAdd(&sstat[128 + col], q);
        }
    }
    __syncthreads();
    // 64-way split of global accumulation to limit same-address contention
    atomicAdd(&partials[(blockIdx.x & 63) * 256 + tid], sstat[tid]);
}

__global__ void finalize_kernel(const float* __restrict__ partials,
                                const float* __restrict__ gamma,
                                const float* __restrict__ beta,
                                float* __restrict__ sb, int E)
{
    const int c = threadIdx.x;   // 0..127
    float s = 0.f, q = 0.f;
    for (int b = 0; b < 64; ++b) {
        s += partials[b * 256 + c];
        q += partials[b * 256 + 128 + c];
    }
    const float inv  = 1.0f / (float)E;
    const float mean = s * inv;
    const float var  = fmaxf(q * inv - mean * mean, 0.f);
    const float sc   = gamma[c] / sqrtf(var + 1e-5f);
    sb[c]       = sc;
    sb[128 + c] = beta[c] - mean * sc;
}

__global__ __launch_bounds__(256) void bn_relu_kernel(float* __restrict__ h,
                                                      const float* __restrict__ sb, int n4)
{
    __shared__ float s_s[128], s_b[128];
    if (threadIdx.x < 128) {
        s_s[threadIdx.x] = sb[threadIdx.x];
        s_b[threadIdx.x] = sb[128 + threadIdx.x];
    }
    __syncthreads();
    int i = blockIdx.x * blockDim.x + threadIdx.x;
    const int stride = gridDim.x * blockDim.x;
    for (; i < n4; i += stride) {
        float4 v = ((float4*)h)[i];
        const int c = (i * 4) & 127;
        v.x = fmaxf(fmaf(v.x, s_s[c + 0], s_b[c + 0]), 0.f);
        v.y = fmaxf(fmaf(v.y, s_s[c + 1], s_b[c + 1]), 0.f);
        v.z = fmaxf(fmaf(v.z, s_s[c + 2], s_b[c + 2]), 0.f);
        v.w = fmaxf(fmaf(v.w, s_s[c + 3], s_b[c + 3]), 0.f);
        ((float4*)h)[i] = v;
    }
}

extern "C" void kernel_launch(void* const* d_in, const int* in_sizes, int n_in,
                              void* d_out, int out_size, void* d_ws, size_t ws_size,
                              hipStream_t stream)
{
    const float* x     = (const float*)d_in[0];
    const int*   nb    = (const int*)d_in[1];      // harness pushes integers as int32
    const float* W     = (const float*)d_in[2];
    const float* gamma = (const float*)d_in[3];
    const float* beta  = (const float*)d_in[4];
    float* out = (float*)d_out;

    const int E = in_sizes[0] / 64;

    // ws layout: [0, 81920) W bf16 | [81920, 147456) partials 64x256 f32 | [147456, 148480) scale/bias
    char* ws = (char*)d_ws;
    unsigned short* Wb       = (unsigned short*)ws;
    float*          partials = (float*)(ws + 81920);
    float*          sb       = (float*)(ws + 81920 + 65536);

    zero_kernel<<<64, 256, 0, stream>>>(partials, 64 * 256);
    convert_w_kernel<<<160, 256, 0, stream>>>(W, Wb, 128 * 320);

    const int nblk = (E + 63) / 64;
    fused_kernel<<<nblk, 256, 0, stream>>>(x, nb, Wb, out, partials, E);

    finalize_kernel<<<1, 128, 0, stream>>>(partials, gamma, beta, sb, E);

    const int n4 = (E * 128) / 4;
    bn_relu_kernel<<<2048, 256, 0, stream>>>(out, sb, n4);
}

// Round 2
// 324.301 us; speedup vs baseline: 1.0693x; 1.0693x over previous
//
#include <hip/hip_runtime.h>
#include <hip/hip_bf16.h>

typedef __attribute__((ext_vector_type(8))) short short8;
typedef __attribute__((ext_vector_type(8))) unsigned short u16x8;
typedef __attribute__((ext_vector_type(4))) float f32x4;

__device__ __forceinline__ unsigned short f2bf(float f) {
    unsigned int u = __float_as_uint(f);
    unsigned int r = (u + 0x7fffu + ((u >> 16) & 1u)) >> 16;   // RNE
    return (unsigned short)r;
}
__device__ __forceinline__ float bf2f(unsigned short u) {
    return __uint_as_float(((unsigned int)u) << 16);
}
__device__ __forceinline__ float4 min4(float4 a, float4 b) {
    return make_float4(fminf(a.x,b.x), fminf(a.y,b.y), fminf(a.z,b.z), fminf(a.w,b.w));
}
__device__ __forceinline__ float4 max4(float4 a, float4 b) {
    return make_float4(fmaxf(a.x,b.x), fmaxf(a.y,b.y), fmaxf(a.z,b.z), fmaxf(a.w,b.w));
}

// zero the stat partials + convert W to bf16, one launch
__global__ __launch_bounds__(256) void prep_kernel(const float* __restrict__ W,
                                                   unsigned short* __restrict__ Wb,
                                                   float* __restrict__ partials) {
    const int i = blockIdx.x * 256 + threadIdx.x;
    if (i < 64 * 256) partials[i] = 0.f;
    if (i < 128 * 320) Wb[i] = f2bf(W[i]);
}

// One block: 32 rows x 128 output channels. K = 320. LDS = 32*320*2 = 20480 B
// -> 8 blocks/CU. XOR swizzle (8B granule): chunk c8 stored at c8 ^ ((row&7)<<1).
template<bool BF16H>
__global__ __launch_bounds__(256, 8) void fused_kernel(
    const float* __restrict__ x, const int* __restrict__ nb,
    const unsigned short* __restrict__ Wb, void* __restrict__ hout,
    float* __restrict__ partials, int E)
{
    __shared__ __align__(16) unsigned short feat[32 * 320];

    const int tid = threadIdx.x;
    const int r0 = blockIdx.x * 32;

    // ---- stage feat tile [x | min01 | max01 | min23 | max23] as bf16, swizzled
    {
        const int lr = tid >> 3;            // local row 0..31
        const int o  = tid & 7;             // 8-col octant within a 64-col section
        const int gr = min(r0 + lr, E - 1);
        int4 nv = *(const int4*)(nb + (long)gr * 4);
        const int i0 = min(max(nv.x, 0), E - 1);
        const int i1 = min(max(nv.y, 0), E - 1);
        const int i2 = min(max(nv.z, 0), E - 1);
        const int i3 = min(max(nv.w, 0), E - 1);
        const int xr = (lr & 7) << 1;
        char* fb = (char*)feat + lr * 640;

        #pragma unroll
        for (int c = 0; c < 2; ++c) {
            const int col = o * 8 + c * 4;
            const float4 xv = *(const float4*)(x + (long)gr * 64 + col);
            const float4 av = *(const float4*)(x + (long)i0 * 64 + col);
            const float4 bv = *(const float4*)(x + (long)i1 * 64 + col);
            const float4 cv = *(const float4*)(x + (long)i2 * 64 + col);
            const float4 dv = *(const float4*)(x + (long)i3 * 64 + col);
            const float4 vals[5] = { xv, min4(av,bv), max4(av,bv), min4(cv,dv), max4(cv,dv) };
            #pragma unroll
            for (int s = 0; s < 5; ++s) {
                const int c8 = s * 16 + o * 2 + c;       // 8B chunk index in row
                ushort4 p;
                p.x = f2bf(vals[s].x); p.y = f2bf(vals[s].y);
                p.z = f2bf(vals[s].z); p.w = f2bf(vals[s].w);
                *(ushort4*)(fb + ((c8 ^ xr) << 3)) = p;
            }
        }
    }
    __syncthreads();

    // ---- MFMA: 4 waves; wave w owns cols [w*32, w*32+32). Each: 32 rows x 32 cols.
    const int lane = tid & 63;
    const int wid  = tid >> 6;
    const int lr16 = lane & 15;
    const int lg   = lane >> 4;             // 0..3
    const int xr   = (lr16 & 7) << 1;

    f32x4 acc[2][2];
    #pragma unroll
    for (int m = 0; m < 2; ++m)
        #pragma unroll
        for (int n = 0; n < 2; ++n)
            acc[m][n] = (f32x4){0.f, 0.f, 0.f, 0.f};

    const char* fb0 = (const char*)feat + lr16 * 640;
    const char* fb1 = (const char*)feat + (16 + lr16) * 640;
    const unsigned short* wb = Wb + (wid * 32 + lr16) * 320 + lg * 8;

    #pragma unroll
    for (int kk = 0; kk < 320; kk += 32) {
        const int c8  = (kk >> 2) + lg * 2;
        const int off = (c8 ^ xr) << 3;
        const short8 a0 = *(const short8*)(fb0 + off);
        const short8 a1 = *(const short8*)(fb1 + off);
        const short8 b0 = *(const short8*)(wb + kk);
        const short8 b1 = *(const short8*)(wb + 16 * 320 + kk);
        acc[0][0] = __builtin_amdgcn_mfma_f32_16x16x32_bf16(a0, b0, acc[0][0], 0, 0, 0);
        acc[0][1] = __builtin_amdgcn_mfma_f32_16x16x32_bf16(a0, b1, acc[0][1], 0, 0, 0);
        acc[1][0] = __builtin_amdgcn_mfma_f32_16x16x32_bf16(a1, b0, acc[1][0], 0, 0, 0);
        acc[1][1] = __builtin_amdgcn_mfma_f32_16x16x32_bf16(a1, b1, acc[1][1], 0, 0, 0);
    }

    // ---- epilogue: write h + per-channel sum/sumsq
    // D layout: col = lane&15, row = (lane>>4)*4 + reg
    float* hf        = (float*)hout;
    unsigned short* hb = (unsigned short*)hout;

    #pragma unroll
    for (int n = 0; n < 2; ++n) {
        const int col = wid * 32 + n * 16 + lr16;
        float s = 0.f, q = 0.f;
        #pragma unroll
        for (int m = 0; m < 2; ++m) {
            const int rbase = r0 + m * 16 + lg * 4;
            #pragma unroll
            for (int j = 0; j < 4; ++j) {
                const int grow = rbase + j;
                const float v = acc[m][n][j];
                if (grow < E) {
                    if (BF16H) hb[(long)grow * 128 + col] = f2bf(v);
                    else       hf[(long)grow * 128 + col] = v;
                    s += v;
                    q += v * v;
                }
            }
        }
        s += __shfl_xor(s, 16); s += __shfl_xor(s, 32);
        q += __shfl_xor(q, 16); q += __shfl_xor(q, 32);
        if (lg == 0) {
            float* base = partials + (blockIdx.x & 63) * 256;
            atomicAdd(&base[col], s);
            atomicAdd(&base[128 + col], q);
        }
    }
}

__global__ void finalize_kernel(const float* __restrict__ partials,
                                const float* __restrict__ gamma,
                                const float* __restrict__ beta,
                                float* __restrict__ sb, int E)
{
    const int c = threadIdx.x;   // 0..127
    float s = 0.f, q = 0.f;
    for (int b = 0; b < 64; ++b) {
        s += partials[b * 256 + c];
        q += partials[b * 256 + 128 + c];
    }
    const float inv  = 1.0f / (float)E;
    const float mean = s * inv;
    const float var  = fmaxf(q * inv - mean * mean, 0.f);
    const float sc   = gamma[c] / sqrtf(var + 1e-5f);
    sb[c]       = sc;
    sb[128 + c] = beta[c] - mean * sc;
}

// bf16-h variant: read 16B (8 bf16), write 32B f32
__global__ __launch_bounds__(256) void bn_relu_bf16_kernel(
    const unsigned short* __restrict__ hb, const float* __restrict__ sb,
    float* __restrict__ out, int n8)
{
    __shared__ float s_s[128], s_b[128];
    if (threadIdx.x < 128) {
        s_s[threadIdx.x] = sb[threadIdx.x];
        s_b[threadIdx.x] = sb[128 + threadIdx.x];
    }
    __syncthreads();
    int i = blockIdx.x * 256 + threadIdx.x;
    const int stride = gridDim.x * 256;
    for (; i < n8; i += stride) {
        const u16x8 v = ((const u16x8*)hb)[i];
        const int c0 = (i & 15) << 3;
        float4 o0, o1;
        o0.x = fmaxf(fmaf(bf2f(v[0]), s_s[c0+0], s_b[c0+0]), 0.f);
        o0.y = fmaxf(fmaf(bf2f(v[1]), s_s[c0+1], s_b[c0+1]), 0.f);
        o0.z = fmaxf(fmaf(bf2f(v[2]), s_s[c0+2], s_b[c0+2]), 0.f);
        o0.w = fmaxf(fmaf(bf2f(v[3]), s_s[c0+3], s_b[c0+3]), 0.f);
        o1.x = fmaxf(fmaf(bf2f(v[4]), s_s[c0+4], s_b[c0+4]), 0.f);
        o1.y = fmaxf(fmaf(bf2f(v[5]), s_s[c0+5], s_b[c0+5]), 0.f);
        o1.z = fmaxf(fmaf(bf2f(v[6]), s_s[c0+6], s_b[c0+6]), 0.f);
        o1.w = fmaxf(fmaf(bf2f(v[7]), s_s[c0+7], s_b[c0+7]), 0.f);
        ((float4*)out)[i * 2]     = o0;
        ((float4*)out)[i * 2 + 1] = o1;
    }
}

// f32 fallback: in-place on d_out
__global__ __launch_bounds__(256) void bn_relu_kernel(float* __restrict__ h,
                                                      const float* __restrict__ sb, int n4)
{
    __shared__ float s_s[128], s_b[128];
    if (threadIdx.x < 128) {
        s_s[threadIdx.x] = sb[threadIdx.x];
        s_b[threadIdx.x] = sb[128 + threadIdx.x];
    }
    __syncthreads();
    int i = blockIdx.x * 256 + threadIdx.x;
    const int stride = gridDim.x * 256;
    for (; i < n4; i += stride) {
        float4 v = ((float4*)h)[i];
        const int c = (i * 4) & 127;
        v.x = fmaxf(fmaf(v.x, s_s[c + 0], s_b[c + 0]), 0.f);
        v.y = fmaxf(fmaf(v.y, s_s[c + 1], s_b[c + 1]), 0.f);
        v.z = fmaxf(fmaf(v.z, s_s[c + 2], s_b[c + 2]), 0.f);
        v.w = fmaxf(fmaf(v.w, s_s[c + 3], s_b[c + 3]), 0.f);
        ((float4*)h)[i] = v;
    }
}

extern "C" void kernel_launch(void* const* d_in, const int* in_sizes, int n_in,
                              void* d_out, int out_size, void* d_ws, size_t ws_size,
                              hipStream_t stream)
{
    const float* x     = (const float*)d_in[0];
    const int*   nb    = (const int*)d_in[1];
    const float* W     = (const float*)d_in[2];
    const float* gamma = (const float*)d_in[3];
    const float* beta  = (const float*)d_in[4];
    float* out = (float*)d_out;

    const int E = in_sizes[0] / 64;

    // ws layout: [0,80K) W bf16 | [80K,144K) partials 64x256 | [144K,+1K) scale/bias | h bf16
    char* ws = (char*)d_ws;
    unsigned short* Wb       = (unsigned short*)ws;
    float*          partials = (float*)(ws + 81920);
    float*          sb       = (float*)(ws + 81920 + 65536);
    unsigned short* hb       = (unsigned short*)(ws + 148480);
    const size_t need = 148480 + (size_t)E * 128 * 2;
    const bool bf16h = (ws_size >= need);

    prep_kernel<<<160, 256, 0, stream>>>(W, Wb, partials);

    const int nblk = (E + 31) / 32;
    if (bf16h) {
        fused_kernel<true><<<nblk, 256, 0, stream>>>(x, nb, Wb, hb, partials, E);
        finalize_kernel<<<1, 128, 0, stream>>>(partials, gamma, beta, sb, E);
        bn_relu_bf16_kernel<<<2048, 256, 0, stream>>>(hb, sb, out, (E * 128) / 8);
    } else {
        fused_kernel<false><<<nblk, 256, 0, stream>>>(x, nb, Wb, out, partials, E);
        finalize_kernel<<<1, 128, 0, stream>>>(partials, gamma, beta, sb, E);
        bn_relu_kernel<<<2048, 256, 0, stream>>>(out, sb, (E * 128) / 4);
    }
}

// Round 3
// 308.453 us; speedup vs baseline: 1.1242x; 1.0514x over previous
//
#include <hip/hip_runtime.h>
#include <hip/hip_bf16.h>

typedef __attribute__((ext_vector_type(8))) short short8;
typedef __attribute__((ext_vector_type(8))) unsigned short u16x8;
typedef __attribute__((ext_vector_type(4))) float f32x4;

__device__ __forceinline__ unsigned short f2bf(float f) {
    unsigned int u = __float_as_uint(f);
    unsigned int r = (u + 0x7fffu + ((u >> 16) & 1u)) >> 16;   // RNE
    return (unsigned short)r;
}
__device__ __forceinline__ float bf2f(unsigned short u) {
    return __uint_as_float(((unsigned int)u) << 16);
}
__device__ __forceinline__ float4 min4(float4 a, float4 b) {
    return make_float4(fminf(a.x,b.x), fminf(a.y,b.y), fminf(a.z,b.z), fminf(a.w,b.w));
}
__device__ __forceinline__ float4 max4(float4 a, float4 b) {
    return make_float4(fmaxf(a.x,b.x), fmaxf(a.y,b.y), fmaxf(a.z,b.z), fmaxf(a.w,b.w));
}

// zero stat partials + convert W to bf16
__global__ __launch_bounds__(256) void prep_kernel(const float* __restrict__ W,
                                                   unsigned short* __restrict__ Wb,
                                                   float* __restrict__ partials) {
    const int i = blockIdx.x * 256 + threadIdx.x;
    if (i < 64 * 256) partials[i] = 0.f;
    if (i < 128 * 320) Wb[i] = f2bf(W[i]);
}

// x (f32) -> xb (bf16), 8 elems/thread
__global__ __launch_bounds__(256) void convert_x_kernel(const float* __restrict__ x,
                                                        unsigned short* __restrict__ xb, long n8) {
    long i = blockIdx.x * 256L + threadIdx.x;
    const long stride = gridDim.x * 256L;
    for (; i < n8; i += stride) {
        const float4 a = ((const float4*)x)[i * 2];
        const float4 b = ((const float4*)x)[i * 2 + 1];
        u16x8 o;
        o[0] = f2bf(a.x); o[1] = f2bf(a.y); o[2] = f2bf(a.z); o[3] = f2bf(a.w);
        o[4] = f2bf(b.x); o[5] = f2bf(b.y); o[6] = f2bf(b.z); o[7] = f2bf(b.w);
        ((u16x8*)xb)[i] = o;
    }
}

// One block: 32 rows x 128 output channels. K = 320. LDS = 32*320*2 = 20480 B
// -> 8 blocks/CU. XOR swizzle on 8B chunks: chunk c8 stored at c8 ^ ((row&7)<<1).
template<bool XB, bool BF16H>
__global__ __launch_bounds__(256, 8) void fused_kernel(
    const float* __restrict__ x, const unsigned short* __restrict__ xb,
    const int* __restrict__ nb,
    const unsigned short* __restrict__ Wb, void* __restrict__ hout,
    float* __restrict__ partials, int E)
{
    __shared__ __align__(16) unsigned short feat[32 * 320];

    const int tid = threadIdx.x;
    const int r0 = blockIdx.x * 32;

    // ---- stage feat tile [x | min01 | max01 | min23 | max23] as bf16, swizzled
    {
        const int lr = tid >> 3;            // local row 0..31
        const int o  = tid & 7;             // 16B chunk within a 64-col section
        const int gr = min(r0 + lr, E - 1);
        int4 nv = *(const int4*)(nb + (long)gr * 4);
        const int i0 = min(max(nv.x, 0), E - 1);
        const int i1 = min(max(nv.y, 0), E - 1);
        const int i2 = min(max(nv.z, 0), E - 1);
        const int i3 = min(max(nv.w, 0), E - 1);
        const int xr = (lr & 7) << 1;
        char* fb = (char*)feat + lr * 640;

        if (XB) {
            const u16x8 xv = *(const u16x8*)(xb + (long)gr * 64 + o * 8);
            const u16x8 av = *(const u16x8*)(xb + (long)i0 * 64 + o * 8);
            const u16x8 bv = *(const u16x8*)(xb + (long)i1 * 64 + o * 8);
            const u16x8 cv = *(const u16x8*)(xb + (long)i2 * 64 + o * 8);
            const u16x8 dv = *(const u16x8*)(xb + (long)i3 * 64 + o * 8);
            u16x8 lo1, hi1, lo2, hi2;
            #pragma unroll
            for (int e = 0; e < 8; ++e) {
                const bool t1 = bf2f(av[e]) < bf2f(bv[e]);
                lo1[e] = t1 ? av[e] : bv[e];
                hi1[e] = t1 ? bv[e] : av[e];
                const bool t2 = bf2f(cv[e]) < bf2f(dv[e]);
                lo2[e] = t2 ? cv[e] : dv[e];
                hi2[e] = t2 ? dv[e] : cv[e];
            }
            const int c8 = o * 2;
            *(u16x8*)(fb + (((c8 +  0) ^ xr) << 3)) = xv;
            *(u16x8*)(fb + (((c8 + 16) ^ xr) << 3)) = lo1;
            *(u16x8*)(fb + (((c8 + 32) ^ xr) << 3)) = hi1;
            *(u16x8*)(fb + (((c8 + 48) ^ xr) << 3)) = lo2;
            *(u16x8*)(fb + (((c8 + 64) ^ xr) << 3)) = hi2;
        } else {
            #pragma unroll
            for (int c = 0; c < 2; ++c) {
                const int col = o * 8 + c * 4;
                const float4 xv = *(const float4*)(x + (long)gr * 64 + col);
                const float4 av = *(const float4*)(x + (long)i0 * 64 + col);
                const float4 bv = *(const float4*)(x + (long)i1 * 64 + col);
                const float4 cv = *(const float4*)(x + (long)i2 * 64 + col);
                const float4 dv = *(const float4*)(x + (long)i3 * 64 + col);
                const float4 vals[5] = { xv, min4(av,bv), max4(av,bv), min4(cv,dv), max4(cv,dv) };
                #pragma unroll
                for (int s = 0; s < 5; ++s) {
                    const int c8 = s * 16 + o * 2 + c;
                    ushort4 p;
                    p.x = f2bf(vals[s].x); p.y = f2bf(vals[s].y);
                    p.z = f2bf(vals[s].z); p.w = f2bf(vals[s].w);
                    *(ushort4*)(fb + ((c8 ^ xr) << 3)) = p;
                }
            }
        }
    }
    __syncthreads();

    // ---- MFMA: 4 waves; wave w owns cols [w*32, w*32+32). Each: 32 rows x 32 cols.
    const int lane = tid & 63;
    const int wid  = tid >> 6;
    const int lr16 = lane & 15;
    const int lg   = lane >> 4;             // 0..3
    const int xr   = (lr16 & 7) << 1;

    f32x4 acc[2][2];
    #pragma unroll
    for (int m = 0; m < 2; ++m)
        #pragma unroll
        for (int n = 0; n < 2; ++n)
            acc[m][n] = (f32x4){0.f, 0.f, 0.f, 0.f};

    const char* fb0 = (const char*)feat + lr16 * 640;
    const char* fb1 = (const char*)feat + (16 + lr16) * 640;
    const unsigned short* wb = Wb + (wid * 32 + lr16) * 320 + lg * 8;

    #pragma unroll
    for (int kk = 0; kk < 320; kk += 32) {
        const int c8  = (kk >> 2) + lg * 2;
        const int off = (c8 ^ xr) << 3;
        const short8 a0 = *(const short8*)(fb0 + off);
        const short8 a1 = *(const short8*)(fb1 + off);
        const short8 b0 = *(const short8*)(wb + kk);
        const short8 b1 = *(const short8*)(wb + 16 * 320 + kk);
        acc[0][0] = __builtin_amdgcn_mfma_f32_16x16x32_bf16(a0, b0, acc[0][0], 0, 0, 0);
        acc[0][1] = __builtin_amdgcn_mfma_f32_16x16x32_bf16(a0, b1, acc[0][1], 0, 0, 0);
        acc[1][0] = __builtin_amdgcn_mfma_f32_16x16x32_bf16(a1, b0, acc[1][0], 0, 0, 0);
        acc[1][1] = __builtin_amdgcn_mfma_f32_16x16x32_bf16(a1, b1, acc[1][1], 0, 0, 0);
    }

    // ---- epilogue: write h + per-channel sum/sumsq
    // D layout: col = lane&15, row = (lane>>4)*4 + reg
    float* hf          = (float*)hout;
    unsigned short* hb = (unsigned short*)hout;

    #pragma unroll
    for (int n = 0; n < 2; ++n) {
        const int col = wid * 32 + n * 16 + lr16;
        float s = 0.f, q = 0.f;
        #pragma unroll
        for (int m = 0; m < 2; ++m) {
            const int rbase = r0 + m * 16 + lg * 4;
            #pragma unroll
            for (int j = 0; j < 4; ++j) {
                const int grow = rbase + j;
                const float v = acc[m][n][j];
                if (grow < E) {
                    if (BF16H) hb[(long)grow * 128 + col] = f2bf(v);
                    else       hf[(long)grow * 128 + col] = v;
                    s += v;
                    q += v * v;
                }
            }
        }
        s += __shfl_xor(s, 16); s += __shfl_xor(s, 32);
        q += __shfl_xor(q, 16); q += __shfl_xor(q, 32);
        if (lg == 0) {
            float* base = partials + (blockIdx.x & 63) * 256;
            atomicAdd(&base[col], s);
            atomicAdd(&base[128 + col], q);
        }
    }
}

__global__ void finalize_kernel(const float* __restrict__ partials,
                                const float* __restrict__ gamma,
                                const float* __restrict__ beta,
                                float* __restrict__ sb, int E)
{
    const int c = threadIdx.x;   // 0..127
    float s = 0.f, q = 0.f;
    for (int b = 0; b < 64; ++b) {
        s += partials[b * 256 + c];
        q += partials[b * 256 + 128 + c];
    }
    const float inv  = 1.0f / (float)E;
    const float mean = s * inv;
    const float var  = fmaxf(q * inv - mean * mean, 0.f);
    const float sc   = gamma[c] / sqrtf(var + 1e-5f);
    sb[c]       = sc;
    sb[128 + c] = beta[c] - mean * sc;
}

// bf16-h variant: read 16B (8 bf16), write 2x16B f32
__global__ __launch_bounds__(256) void bn_relu_bf16_kernel(
    const unsigned short* __restrict__ hb, const float* __restrict__ sb,
    float* __restrict__ out, long n8)
{
    __shared__ float s_s[128], s_b[128];
    if (threadIdx.x < 128) {
        s_s[threadIdx.x] = sb[threadIdx.x];
        s_b[threadIdx.x] = sb[128 + threadIdx.x];
    }
    __syncthreads();
    long i = blockIdx.x * 256L + threadIdx.x;
    const long stride = gridDim.x * 256L;
    for (; i < n8; i += stride) {
        const u16x8 v = ((const u16x8*)hb)[i];
        const int c0 = ((int)i & 15) << 3;
        float4 o0, o1;
        o0.x = fmaxf(fmaf(bf2f(v[0]), s_s[c0+0], s_b[c0+0]), 0.f);
        o0.y = fmaxf(fmaf(bf2f(v[1]), s_s[c0+1], s_b[c0+1]), 0.f);
        o0.z = fmaxf(fmaf(bf2f(v[2]), s_s[c0+2], s_b[c0+2]), 0.f);
        o0.w = fmaxf(fmaf(bf2f(v[3]), s_s[c0+3], s_b[c0+3]), 0.f);
        o1.x = fmaxf(fmaf(bf2f(v[4]), s_s[c0+4], s_b[c0+4]), 0.f);
        o1.y = fmaxf(fmaf(bf2f(v[5]), s_s[c0+5], s_b[c0+5]), 0.f);
        o1.z = fmaxf(fmaf(bf2f(v[6]), s_s[c0+6], s_b[c0+6]), 0.f);
        o1.w = fmaxf(fmaf(bf2f(v[7]), s_s[c0+7], s_b[c0+7]), 0.f);
        ((float4*)out)[i * 2]     = o0;
        ((float4*)out)[i * 2 + 1] = o1;
    }
}

// f32 fallback: in-place on d_out
__global__ __launch_bounds__(256) void bn_relu_kernel(float* __restrict__ h,
                                                      const float* __restrict__ sb, long n4)
{
    __shared__ float s_s[128], s_b[128];
    if (threadIdx.x < 128) {
        s_s[threadIdx.x] = sb[threadIdx.x];
        s_b[threadIdx.x] = sb[128 + threadIdx.x];
    }
    __syncthreads();
    long i = blockIdx.x * 256L + threadIdx.x;
    const long stride = gridDim.x * 256L;
    for (; i < n4; i += stride) {
        float4 v = ((float4*)h)[i];
        const int c = ((int)i * 4) & 127;
        v.x = fmaxf(fmaf(v.x, s_s[c + 0], s_b[c + 0]), 0.f);
        v.y = fmaxf(fmaf(v.y, s_s[c + 1], s_b[c + 1]), 0.f);
        v.z = fmaxf(fmaf(v.z, s_s[c + 2], s_b[c + 2]), 0.f);
        v.w = fmaxf(fmaf(v.w, s_s[c + 3], s_b[c + 3]), 0.f);
        ((float4*)h)[i] = v;
    }
}

extern "C" void kernel_launch(void* const* d_in, const int* in_sizes, int n_in,
                              void* d_out, int out_size, void* d_ws, size_t ws_size,
                              hipStream_t stream)
{
    const float* x     = (const float*)d_in[0];
    const int*   nb    = (const int*)d_in[1];
    const float* W     = (const float*)d_in[2];
    const float* gamma = (const float*)d_in[3];
    const float* beta  = (const float*)d_in[4];
    float* out = (float*)d_out;

    const int E = in_sizes[0] / 64;

    // ws layout: Wb 80K | partials 64K | sb 1K | xb (E*128 B) | hb (E*256 B)
    char* ws = (char*)d_ws;
    unsigned short* Wb       = (unsigned short*)ws;
    float*          partials = (float*)(ws + 81920);
    float*          sb       = (float*)(ws + 81920 + 65536);
    unsigned short* xb       = (unsigned short*)(ws + 148480);
    const size_t xb_end = 148480 + (size_t)E * 128;
    unsigned short* hb       = (unsigned short*)(ws + xb_end);
    const bool have_xb = (ws_size >= xb_end);
    const bool have_hb = (ws_size >= xb_end + (size_t)E * 256);

    prep_kernel<<<160, 256, 0, stream>>>(W, Wb, partials);
    if (have_xb)
        convert_x_kernel<<<2048, 256, 0, stream>>>(x, xb, (long)E * 8);

    const int nblk = (E + 31) / 32;
    void* hdst = have_hb ? (void*)hb : (void*)out;
    if (have_xb && have_hb)
        fused_kernel<true,  true ><<<nblk, 256, 0, stream>>>(x, xb, nb, Wb, hdst, partials, E);
    else if (have_xb)
        fused_kernel<true,  false><<<nblk, 256, 0, stream>>>(x, xb, nb, Wb, hdst, partials, E);
    else if (have_hb)
        fused_kernel<false, true ><<<nblk, 256, 0, stream>>>(x, xb, nb, Wb, hdst, partials, E);
    else
        fused_kernel<false, false><<<nblk, 256, 0, stream>>>(x, xb, nb, Wb, hdst, partials, E);

    finalize_kernel<<<1, 128, 0, stream>>>(partials, gamma, beta, sb, E);

    if (have_hb)
        bn_relu_bf16_kernel<<<2048, 256, 0, stream>>>(hb, sb, out, (long)E * 16);
    else
        bn_relu_kernel<<<2048, 256, 0, stream>>>(out, sb, (long)E * 32);
}

// Round 4
// 294.265 us; speedup vs baseline: 1.1785x; 1.0482x over previous
//
#include <hip/hip_runtime.h>
#include <hip/hip_bf16.h>

typedef __attribute__((ext_vector_type(8))) short short8;
typedef __attribute__((ext_vector_type(8))) unsigned short u16x8;
typedef __attribute__((ext_vector_type(4))) float f32x4;

__device__ __forceinline__ unsigned short f2bf(float f) {
    unsigned int u = __float_as_uint(f);
    unsigned int r = (u + 0x7fffu + ((u >> 16) & 1u)) >> 16;   // RNE
    return (unsigned short)r;
}
__device__ __forceinline__ float bf2f(unsigned short u) {
    return __uint_as_float(((unsigned int)u) << 16);
}
__device__ __forceinline__ float4 min4(float4 a, float4 b) {
    return make_float4(fminf(a.x,b.x), fminf(a.y,b.y), fminf(a.z,b.z), fminf(a.w,b.w));
}
__device__ __forceinline__ float4 max4(float4 a, float4 b) {
    return make_float4(fmaxf(a.x,b.x), fmaxf(a.y,b.y), fmaxf(a.z,b.z), fmaxf(a.w,b.w));
}

// fallback-only: zero stat partials + convert W to bf16
__global__ __launch_bounds__(256) void prep_kernel(const float* __restrict__ W,
                                                   unsigned short* __restrict__ Wb,
                                                   float* __restrict__ partials) {
    const int i = blockIdx.x * 256 + threadIdx.x;
    if (i < 64 * 256) partials[i] = 0.f;
    if (i < 128 * 320) Wb[i] = f2bf(W[i]);
}

// combined: zero partials + W->bf16 + x->bf16 (one launch)
__global__ __launch_bounds__(256) void prep_conv_kernel(
    const float* __restrict__ W, unsigned short* __restrict__ Wb,
    float* __restrict__ partials,
    const float* __restrict__ x, unsigned short* __restrict__ xb, long n8)
{
    const long g = blockIdx.x * 256L + threadIdx.x;
    if (g < 64 * 256) partials[g] = 0.f;
    if (g < 128 * 320) Wb[g] = f2bf(W[g]);
    const long stride = gridDim.x * 256L;
    for (long i = g; i < n8; i += stride) {
        const float4 a = ((const float4*)x)[i * 2];
        const float4 b = ((const float4*)x)[i * 2 + 1];
        u16x8 o;
        o[0] = f2bf(a.x); o[1] = f2bf(a.y); o[2] = f2bf(a.z); o[3] = f2bf(a.w);
        o[4] = f2bf(b.x); o[5] = f2bf(b.y); o[6] = f2bf(b.z); o[7] = f2bf(b.w);
        ((u16x8*)xb)[i] = o;
    }
}

// One block: 32 rows x 128 output channels. K = 320. LDS = 32*320*2 = 20480 B
// -> 8 blocks/CU. XOR swizzle on 8B chunks: chunk c8 stored at c8 ^ ((row&7)<<1).
template<bool XB, bool BF16H>
__global__ __launch_bounds__(256, 8) void fused_kernel(
    const float* __restrict__ x, const unsigned short* __restrict__ xb,
    const int* __restrict__ nb,
    const unsigned short* __restrict__ Wb, void* __restrict__ hout,
    float* __restrict__ partials, int E)
{
    __shared__ __align__(16) unsigned short feat[32 * 320];

    const int tid = threadIdx.x;
    const int r0 = blockIdx.x * 32;

    // ---- stage feat tile [x | min01 | max01 | min23 | max23] as bf16, swizzled
    {
        const int lr = tid >> 3;            // local row 0..31
        const int o  = tid & 7;             // 16B chunk within a 64-col section
        const int gr = min(r0 + lr, E - 1);
        int4 nv = *(const int4*)(nb + (long)gr * 4);
        const int i0 = min(max(nv.x, 0), E - 1);
        const int i1 = min(max(nv.y, 0), E - 1);
        const int i2 = min(max(nv.z, 0), E - 1);
        const int i3 = min(max(nv.w, 0), E - 1);
        const int xr = (lr & 7) << 1;
        char* fb = (char*)feat + lr * 640;

        if (XB) {
            const u16x8 xv = *(const u16x8*)(xb + (long)gr * 64 + o * 8);
            const u16x8 av = *(const u16x8*)(xb + (long)i0 * 64 + o * 8);
            const u16x8 bv = *(const u16x8*)(xb + (long)i1 * 64 + o * 8);
            const u16x8 cv = *(const u16x8*)(xb + (long)i2 * 64 + o * 8);
            const u16x8 dv = *(const u16x8*)(xb + (long)i3 * 64 + o * 8);
            u16x8 lo1, hi1, lo2, hi2;
            #pragma unroll
            for (int e = 0; e < 8; ++e) {
                const bool t1 = bf2f(av[e]) < bf2f(bv[e]);
                lo1[e] = t1 ? av[e] : bv[e];
                hi1[e] = t1 ? bv[e] : av[e];
                const bool t2 = bf2f(cv[e]) < bf2f(dv[e]);
                lo2[e] = t2 ? cv[e] : dv[e];
                hi2[e] = t2 ? dv[e] : cv[e];
            }
            const int c8 = o * 2;
            *(u16x8*)(fb + (((c8 +  0) ^ xr) << 3)) = xv;
            *(u16x8*)(fb + (((c8 + 16) ^ xr) << 3)) = lo1;
            *(u16x8*)(fb + (((c8 + 32) ^ xr) << 3)) = hi1;
            *(u16x8*)(fb + (((c8 + 48) ^ xr) << 3)) = lo2;
            *(u16x8*)(fb + (((c8 + 64) ^ xr) << 3)) = hi2;
        } else {
            #pragma unroll
            for (int c = 0; c < 2; ++c) {
                const int col = o * 8 + c * 4;
                const float4 xv = *(const float4*)(x + (long)gr * 64 + col);
                const float4 av = *(const float4*)(x + (long)i0 * 64 + col);
                const float4 bv = *(const float4*)(x + (long)i1 * 64 + col);
                const float4 cv = *(const float4*)(x + (long)i2 * 64 + col);
                const float4 dv = *(const float4*)(x + (long)i3 * 64 + col);
                const float4 vals[5] = { xv, min4(av,bv), max4(av,bv), min4(cv,dv), max4(cv,dv) };
                #pragma unroll
                for (int s = 0; s < 5; ++s) {
                    const int c8 = s * 16 + o * 2 + c;
                    ushort4 p;
                    p.x = f2bf(vals[s].x); p.y = f2bf(vals[s].y);
                    p.z = f2bf(vals[s].z); p.w = f2bf(vals[s].w);
                    *(ushort4*)(fb + ((c8 ^ xr) << 3)) = p;
                }
            }
        }
    }
    __syncthreads();

    // ---- MFMA: 4 waves; wave w owns cols [w*32, w*32+32). Each: 32 rows x 32 cols.
    const int lane = tid & 63;
    const int wid  = tid >> 6;
    const int lr16 = lane & 15;
    const int lg   = lane >> 4;             // 0..3
    const int xr   = (lr16 & 7) << 1;

    f32x4 acc[2][2];
    #pragma unroll
    for (int m = 0; m < 2; ++m)
        #pragma unroll
        for (int n = 0; n < 2; ++n)
            acc[m][n] = (f32x4){0.f, 0.f, 0.f, 0.f};

    const char* fb0 = (const char*)feat + lr16 * 640;
    const char* fb1 = (const char*)feat + (16 + lr16) * 640;
    const unsigned short* wb = Wb + (wid * 32 + lr16) * 320 + lg * 8;

    #pragma unroll
    for (int kk = 0; kk < 320; kk += 32) {
        const int c8  = (kk >> 2) + lg * 2;
        const int off = (c8 ^ xr) << 3;
        const short8 a0 = *(const short8*)(fb0 + off);
        const short8 a1 = *(const short8*)(fb1 + off);
        const short8 b0 = *(const short8*)(wb + kk);
        const short8 b1 = *(const short8*)(wb + 16 * 320 + kk);
        acc[0][0] = __builtin_amdgcn_mfma_f32_16x16x32_bf16(a0, b0, acc[0][0], 0, 0, 0);
        acc[0][1] = __builtin_amdgcn_mfma_f32_16x16x32_bf16(a0, b1, acc[0][1], 0, 0, 0);
        acc[1][0] = __builtin_amdgcn_mfma_f32_16x16x32_bf16(a1, b0, acc[1][0], 0, 0, 0);
        acc[1][1] = __builtin_amdgcn_mfma_f32_16x16x32_bf16(a1, b1, acc[1][1], 0, 0, 0);
    }

    // ---- stats from regs (D layout: col = lane&15, row = (lane>>4)*4 + reg)
    #pragma unroll
    for (int n = 0; n < 2; ++n) {
        const int col = wid * 32 + n * 16 + lr16;
        float s = 0.f, q = 0.f;
        #pragma unroll
        for (int m = 0; m < 2; ++m) {
            const int rbase = r0 + m * 16 + lg * 4;
            #pragma unroll
            for (int j = 0; j < 4; ++j) {
                if (rbase + j < E) {
                    const float v = acc[m][n][j];
                    s += v;
                    q += v * v;
                }
            }
        }
        s += __shfl_xor(s, 16); s += __shfl_xor(s, 32);
        q += __shfl_xor(q, 16); q += __shfl_xor(q, 32);
        if (lg == 0) {
            float* base = partials + (blockIdx.x & 63) * 256;
            atomicAdd(&base[col], s);
            atomicAdd(&base[128 + col], q);
        }
    }

    if (BF16H) {
        // ---- transpose acc through LDS (reuse feat), then coalesced 16B stores
        __syncthreads();                      // all waves done reading feat
        unsigned short* hsm = feat;           // 32 rows x pitch 132 = 8448 B
        #pragma unroll
        for (int m = 0; m < 2; ++m) {
            const int rb = m * 16 + lg * 4;
            #pragma unroll
            for (int n = 0; n < 2; ++n) {
                const int col = wid * 32 + n * 16 + lr16;
                #pragma unroll
                for (int j = 0; j < 4; ++j)
                    hsm[(rb + j) * 132 + col] = f2bf(acc[m][n][j]);
            }
        }
        __syncthreads();
        unsigned short* hb = (unsigned short*)hout;
        const int oct = tid & 15;             // 8-col chunk
        const int lrr = tid >> 4;             // 0..15
        #pragma unroll
        for (int it = 0; it < 2; ++it) {
            const int r = lrr + it * 16;
            const int grow = r0 + r;
            if (grow < E)
                *(u16x8*)(hb + (long)grow * 128 + oct * 8) =
                    *(const u16x8*)(hsm + r * 132 + oct * 8);
        }
    } else {
        float* hf = (float*)hout;
        #pragma unroll
        for (int n = 0; n < 2; ++n) {
            const int col = wid * 32 + n * 16 + lr16;
            #pragma unroll
            for (int m = 0; m < 2; ++m) {
                const int rbase = r0 + m * 16 + lg * 4;
                #pragma unroll
                for (int j = 0; j < 4; ++j) {
                    const int grow = rbase + j;
                    if (grow < E) hf[(long)grow * 128 + col] = acc[m][n][j];
                }
            }
        }
    }
}

__global__ void finalize_kernel(const float* __restrict__ partials,
                                const float* __restrict__ gamma,
                                const float* __restrict__ beta,
                                float* __restrict__ sb, int E)
{
    const int c = threadIdx.x;   // 0..127
    float s = 0.f, q = 0.f;
    for (int b = 0; b < 64; ++b) {
        s += partials[b * 256 + c];
        q += partials[b * 256 + 128 + c];
    }
    const float inv  = 1.0f / (float)E;
    const float mean = s * inv;
    const float var  = fmaxf(q * inv - mean * mean, 0.f);
    const float sc   = gamma[c] / sqrtf(var + 1e-5f);
    sb[c]       = sc;
    sb[128 + c] = beta[c] - mean * sc;
}

// bf16-h variant: read 16B (8 bf16), write 2x16B f32
__global__ __launch_bounds__(256) void bn_relu_bf16_kernel(
    const unsigned short* __restrict__ hb, const float* __restrict__ sb,
    float* __restrict__ out, long n8)
{
    __shared__ float s_s[128], s_b[128];
    if (threadIdx.x < 128) {
        s_s[threadIdx.x] = sb[threadIdx.x];
        s_b[threadIdx.x] = sb[128 + threadIdx.x];
    }
    __syncthreads();
    long i = blockIdx.x * 256L + threadIdx.x;
    const long stride = gridDim.x * 256L;
    for (; i < n8; i += stride) {
        const u16x8 v = ((const u16x8*)hb)[i];
        const int c0 = ((int)i & 15) << 3;
        float4 o0, o1;
        o0.x = fmaxf(fmaf(bf2f(v[0]), s_s[c0+0], s_b[c0+0]), 0.f);
        o0.y = fmaxf(fmaf(bf2f(v[1]), s_s[c0+1], s_b[c0+1]), 0.f);
        o0.z = fmaxf(fmaf(bf2f(v[2]), s_s[c0+2], s_b[c0+2]), 0.f);
        o0.w = fmaxf(fmaf(bf2f(v[3]), s_s[c0+3], s_b[c0+3]), 0.f);
        o1.x = fmaxf(fmaf(bf2f(v[4]), s_s[c0+4], s_b[c0+4]), 0.f);
        o1.y = fmaxf(fmaf(bf2f(v[5]), s_s[c0+5], s_b[c0+5]), 0.f);
        o1.z = fmaxf(fmaf(bf2f(v[6]), s_s[c0+6], s_b[c0+6]), 0.f);
        o1.w = fmaxf(fmaf(bf2f(v[7]), s_s[c0+7], s_b[c0+7]), 0.f);
        ((float4*)out)[i * 2]     = o0;
        ((float4*)out)[i * 2 + 1] = o1;
    }
}

// f32 fallback: in-place on d_out
__global__ __launch_bounds__(256) void bn_relu_kernel(float* __restrict__ h,
                                                      const float* __restrict__ sb, long n4)
{
    __shared__ float s_s[128], s_b[128];
    if (threadIdx.x < 128) {
        s_s[threadIdx.x] = sb[threadIdx.x];
        s_b[threadIdx.x] = sb[128 + threadIdx.x];
    }
    __syncthreads();
    long i = blockIdx.x * 256L + threadIdx.x;
    const long stride = gridDim.x * 256L;
    for (; i < n4; i += stride) {
        float4 v = ((float4*)h)[i];
        const int c = ((int)i * 4) & 127;
        v.x = fmaxf(fmaf(v.x, s_s[c + 0], s_b[c + 0]), 0.f);
        v.y = fmaxf(fmaf(v.y, s_s[c + 1], s_b[c + 1]), 0.f);
        v.z = fmaxf(fmaf(v.z, s_s[c + 2], s_b[c + 2]), 0.f);
        v.w = fmaxf(fmaf(v.w, s_s[c + 3], s_b[c + 3]), 0.f);
        ((float4*)h)[i] = v;
    }
}

extern "C" void kernel_launch(void* const* d_in, const int* in_sizes, int n_in,
                              void* d_out, int out_size, void* d_ws, size_t ws_size,
                              hipStream_t stream)
{
    const float* x     = (const float*)d_in[0];
    const int*   nb    = (const int*)d_in[1];
    const float* W     = (const float*)d_in[2];
    const float* gamma = (const float*)d_in[3];
    const float* beta  = (const float*)d_in[4];
    float* out = (float*)d_out;

    const int E = in_sizes[0] / 64;

    // ws layout: Wb 80K | partials 64K | sb 1K | xb (E*128 B) | hb (E*256 B)
    char* ws = (char*)d_ws;
    unsigned short* Wb       = (unsigned short*)ws;
    float*          partials = (float*)(ws + 81920);
    float*          sb       = (float*)(ws + 81920 + 65536);
    unsigned short* xb       = (unsigned short*)(ws + 148480);
    const size_t xb_end = 148480 + (size_t)E * 128;
    unsigned short* hb       = (unsigned short*)(ws + xb_end);
    const bool have_xb = (ws_size >= xb_end);
    const bool have_hb = (ws_size >= xb_end + (size_t)E * 256);

    if (have_xb)
        prep_conv_kernel<<<2048, 256, 0, stream>>>(W, Wb, partials, x, xb, (long)E * 8);
    else
        prep_kernel<<<160, 256, 0, stream>>>(W, Wb, partials);

    const int nblk = (E + 31) / 32;
    void* hdst = have_hb ? (void*)hb : (void*)out;
    if (have_xb && have_hb)
        fused_kernel<true,  true ><<<nblk, 256, 0, stream>>>(x, xb, nb, Wb, hdst, partials, E);
    else if (have_xb)
        fused_kernel<true,  false><<<nblk, 256, 0, stream>>>(x, xb, nb, Wb, hdst, partials, E);
    else if (have_hb)
        fused_kernel<false, true ><<<nblk, 256, 0, stream>>>(x, xb, nb, Wb, hdst, partials, E);
    else
        fused_kernel<false, false><<<nblk, 256, 0, stream>>>(x, xb, nb, Wb, hdst, partials, E);

    finalize_kernel<<<1, 128, 0, stream>>>(partials, gamma, beta, sb, E);

    if (have_hb)
        bn_relu_bf16_kernel<<<2048, 256, 0, stream>>>(hb, sb, out, (long)E * 16);
    else
        bn_relu_kernel<<<2048, 256, 0, stream>>>(out, sb, (long)E * 32);
}

// Round 6
// 293.930 us; speedup vs baseline: 1.1798x; 1.0011x over previous
//
#include <hip/hip_runtime.h>
#include <hip/hip_bf16.h>

typedef __attribute__((ext_vector_type(8))) short short8;
typedef __attribute__((ext_vector_type(8))) unsigned short u16x8;
typedef __attribute__((ext_vector_type(4))) float f32x4;

__device__ __forceinline__ unsigned short f2bf(float f) {
    unsigned int u = __float_as_uint(f);
    unsigned int r = (u + 0x7fffu + ((u >> 16) & 1u)) >> 16;   // RNE
    return (unsigned short)r;
}
__device__ __forceinline__ float bf2f(unsigned short u) {
    return __uint_as_float(((unsigned int)u) << 16);
}
__device__ __forceinline__ float4 min4(float4 a, float4 b) {
    return make_float4(fminf(a.x,b.x), fminf(a.y,b.y), fminf(a.z,b.z), fminf(a.w,b.w));
}
__device__ __forceinline__ float4 max4(float4 a, float4 b) {
    return make_float4(fmaxf(a.x,b.x), fmaxf(a.y,b.y), fmaxf(a.z,b.z), fmaxf(a.w,b.w));
}

// fallback-only: zero stat partials + convert W to bf16
__global__ __launch_bounds__(256) void prep_kernel(const float* __restrict__ W,
                                                   unsigned short* __restrict__ Wb,
                                                   float* __restrict__ partials) {
    const int i = blockIdx.x * 256 + threadIdx.x;
    if (i < 64 * 256) partials[i] = 0.f;
    if (i < 128 * 320) Wb[i] = f2bf(W[i]);
}

// combined: zero partials + W->bf16 + x->bf16 (one launch). x reads are NT
// (f32 x is never touched again); xb/Wb writes stay cached (we WANT them in L3).
__global__ __launch_bounds__(256) void prep_conv_kernel(
    const float* __restrict__ W, unsigned short* __restrict__ Wb,
    float* __restrict__ partials,
    const float* __restrict__ x, unsigned short* __restrict__ xb, long n8)
{
    const long g = blockIdx.x * 256L + threadIdx.x;
    if (g < 64 * 256) partials[g] = 0.f;
    if (g < 128 * 320) Wb[g] = f2bf(W[g]);
    const long stride = gridDim.x * 256L;
    for (long i = g; i < n8; i += stride) {
        const f32x4 a = __builtin_nontemporal_load(((const f32x4*)x) + i * 2);
        const f32x4 b = __builtin_nontemporal_load(((const f32x4*)x) + i * 2 + 1);
        u16x8 o;
        o[0] = f2bf(a[0]); o[1] = f2bf(a[1]); o[2] = f2bf(a[2]); o[3] = f2bf(a[3]);
        o[4] = f2bf(b[0]); o[5] = f2bf(b[1]); o[6] = f2bf(b[2]); o[7] = f2bf(b[3]);
        ((u16x8*)xb)[i] = o;
    }
}

// One block: 32 rows x 128 output channels. K = 320. LDS = 32*320*2 = 20480 B
// -> 8 blocks/CU. XOR swizzle on 8B chunks: chunk c8 stored at c8 ^ ((row&7)<<1).
// h writes are NON-TEMPORAL so the 140MB/dispatch write stream doesn't evict
// xb (64MB) from the Infinity Cache -> gathers stay L3-resident.
template<bool XB, bool BF16H>
__global__ __launch_bounds__(256, 8) void fused_kernel(
    const float* __restrict__ x, const unsigned short* __restrict__ xb,
    const int* __restrict__ nb,
    const unsigned short* __restrict__ Wb, void* __restrict__ hout,
    float* __restrict__ partials, int E)
{
    __shared__ __align__(16) unsigned short feat[32 * 320];

    const int tid = threadIdx.x;
    const int r0 = blockIdx.x * 32;

    // ---- stage feat tile [x | min01 | max01 | min23 | max23] as bf16, swizzled
    {
        const int lr = tid >> 3;            // local row 0..31
        const int o  = tid & 7;             // 16B chunk within a 64-col section
        const int gr = min(r0 + lr, E - 1);
        int4 nv = *(const int4*)(nb + (long)gr * 4);
        const int i0 = min(max(nv.x, 0), E - 1);
        const int i1 = min(max(nv.y, 0), E - 1);
        const int i2 = min(max(nv.z, 0), E - 1);
        const int i3 = min(max(nv.w, 0), E - 1);
        const int xr = (lr & 7) << 1;
        char* fb = (char*)feat + lr * 640;

        if (XB) {
            const u16x8 xv = *(const u16x8*)(xb + (long)gr * 64 + o * 8);
            const u16x8 av = *(const u16x8*)(xb + (long)i0 * 64 + o * 8);
            const u16x8 bv = *(const u16x8*)(xb + (long)i1 * 64 + o * 8);
            const u16x8 cv = *(const u16x8*)(xb + (long)i2 * 64 + o * 8);
            const u16x8 dv = *(const u16x8*)(xb + (long)i3 * 64 + o * 8);
            u16x8 lo1, hi1, lo2, hi2;
            #pragma unroll
            for (int e = 0; e < 8; ++e) {
                const bool t1 = bf2f(av[e]) < bf2f(bv[e]);
                lo1[e] = t1 ? av[e] : bv[e];
                hi1[e] = t1 ? bv[e] : av[e];
                const bool t2 = bf2f(cv[e]) < bf2f(dv[e]);
                lo2[e] = t2 ? cv[e] : dv[e];
                hi2[e] = t2 ? dv[e] : cv[e];
            }
            const int c8 = o * 2;
            *(u16x8*)(fb + (((c8 +  0) ^ xr) << 3)) = xv;
            *(u16x8*)(fb + (((c8 + 16) ^ xr) << 3)) = lo1;
            *(u16x8*)(fb + (((c8 + 32) ^ xr) << 3)) = hi1;
            *(u16x8*)(fb + (((c8 + 48) ^ xr) << 3)) = lo2;
            *(u16x8*)(fb + (((c8 + 64) ^ xr) << 3)) = hi2;
        } else {
            #pragma unroll
            for (int c = 0; c < 2; ++c) {
                const int col = o * 8 + c * 4;
                const float4 xv = *(const float4*)(x + (long)gr * 64 + col);
                const float4 av = *(const float4*)(x + (long)i0 * 64 + col);
                const float4 bv = *(const float4*)(x + (long)i1 * 64 + col);
                const float4 cv = *(const float4*)(x + (long)i2 * 64 + col);
                const float4 dv = *(const float4*)(x + (long)i3 * 64 + col);
                const float4 vals[5] = { xv, min4(av,bv), max4(av,bv), min4(cv,dv), max4(cv,dv) };
                #pragma unroll
                for (int s = 0; s < 5; ++s) {
                    const int c8 = s * 16 + o * 2 + c;
                    ushort4 p;
                    p.x = f2bf(vals[s].x); p.y = f2bf(vals[s].y);
                    p.z = f2bf(vals[s].z); p.w = f2bf(vals[s].w);
                    *(ushort4*)(fb + ((c8 ^ xr) << 3)) = p;
                }
            }
        }
    }
    __syncthreads();

    // ---- MFMA: 4 waves; wave w owns cols [w*32, w*32+32). Each: 32 rows x 32 cols.
    const int lane = tid & 63;
    const int wid  = tid >> 6;
    const int lr16 = lane & 15;
    const int lg   = lane >> 4;             // 0..3
    const int xr   = (lr16 & 7) << 1;

    f32x4 acc[2][2];
    #pragma unroll
    for (int m = 0; m < 2; ++m)
        #pragma unroll
        for (int n = 0; n < 2; ++n)
            acc[m][n] = (f32x4){0.f, 0.f, 0.f, 0.f};

    const char* fb0 = (const char*)feat + lr16 * 640;
    const char* fb1 = (const char*)feat + (16 + lr16) * 640;
    const unsigned short* wb = Wb + (wid * 32 + lr16) * 320 + lg * 8;

    #pragma unroll
    for (int kk = 0; kk < 320; kk += 32) {
        const int c8  = (kk >> 2) + lg * 2;
        const int off = (c8 ^ xr) << 3;
        const short8 a0 = *(const short8*)(fb0 + off);
        const short8 a1 = *(const short8*)(fb1 + off);
        const short8 b0 = *(const short8*)(wb + kk);
        const short8 b1 = *(const short8*)(wb + 16 * 320 + kk);
        acc[0][0] = __builtin_amdgcn_mfma_f32_16x16x32_bf16(a0, b0, acc[0][0], 0, 0, 0);
        acc[0][1] = __builtin_amdgcn_mfma_f32_16x16x32_bf16(a0, b1, acc[0][1], 0, 0, 0);
        acc[1][0] = __builtin_amdgcn_mfma_f32_16x16x32_bf16(a1, b0, acc[1][0], 0, 0, 0);
        acc[1][1] = __builtin_amdgcn_mfma_f32_16x16x32_bf16(a1, b1, acc[1][1], 0, 0, 0);
    }

    // ---- stats from regs (D layout: col = lane&15, row = (lane>>4)*4 + reg)
    #pragma unroll
    for (int n = 0; n < 2; ++n) {
        const int col = wid * 32 + n * 16 + lr16;
        float s = 0.f, q = 0.f;
        #pragma unroll
        for (int m = 0; m < 2; ++m) {
            const int rbase = r0 + m * 16 + lg * 4;
            #pragma unroll
            for (int j = 0; j < 4; ++j) {
                if (rbase + j < E) {
                    const float v = acc[m][n][j];
                    s += v;
                    q += v * v;
                }
            }
        }
        s += __shfl_xor(s, 16); s += __shfl_xor(s, 32);
        q += __shfl_xor(q, 16); q += __shfl_xor(q, 32);
        if (lg == 0) {
            float* base = partials + (blockIdx.x & 63) * 256;
            atomicAdd(&base[col], s);
            atomicAdd(&base[128 + col], q);
        }
    }

    if (BF16H) {
        // ---- transpose acc through LDS (reuse feat), then coalesced NT 16B stores
        __syncthreads();                      // all waves done reading feat
        unsigned short* hsm = feat;           // 32 rows x pitch 132 = 8448 B
        #pragma unroll
        for (int m = 0; m < 2; ++m) {
            const int rb = m * 16 + lg * 4;
            #pragma unroll
            for (int n = 0; n < 2; ++n) {
                const int col = wid * 32 + n * 16 + lr16;
                #pragma unroll
                for (int j = 0; j < 4; ++j)
                    hsm[(rb + j) * 132 + col] = f2bf(acc[m][n][j]);
            }
        }
        __syncthreads();
        unsigned short* hb = (unsigned short*)hout;
        const int oct = tid & 15;             // 8-col chunk
        const int lrr = tid >> 4;             // 0..15
        #pragma unroll
        for (int it = 0; it < 2; ++it) {
            const int r = lrr + it * 16;
            const int grow = r0 + r;
            if (grow < E)
                __builtin_nontemporal_store(
                    *(const u16x8*)(hsm + r * 132 + oct * 8),
                    (u16x8*)(hb + (long)grow * 128 + oct * 8));
        }
    } else {
        float* hf = (float*)hout;
        #pragma unroll
        for (int n = 0; n < 2; ++n) {
            const int col = wid * 32 + n * 16 + lr16;
            #pragma unroll
            for (int m = 0; m < 2; ++m) {
                const int rbase = r0 + m * 16 + lg * 4;
                #pragma unroll
                for (int j = 0; j < 4; ++j) {
                    const int grow = rbase + j;
                    if (grow < E)
                        __builtin_nontemporal_store(acc[m][n][j],
                            hf + (long)grow * 128 + col);
                }
            }
        }
    }
}

__global__ void finalize_kernel(const float* __restrict__ partials,
                                const float* __restrict__ gamma,
                                const float* __restrict__ beta,
                                float* __restrict__ sb, int E)
{
    const int c = threadIdx.x;   // 0..127
    float s = 0.f, q = 0.f;
    for (int b = 0; b < 64; ++b) {
        s += partials[b * 256 + c];
        q += partials[b * 256 + 128 + c];
    }
    const float inv  = 1.0f / (float)E;
    const float mean = s * inv;
    const float var  = fmaxf(q * inv - mean * mean, 0.f);
    const float sc   = gamma[c] / sqrtf(var + 1e-5f);
    sb[c]       = sc;
    sb[128 + c] = beta[c] - mean * sc;
}

// bf16-h variant: NT-read 16B (8 bf16), NT-write 2x16B f32
__global__ __launch_bounds__(256) void bn_relu_bf16_kernel(
    const unsigned short* __restrict__ hb, const float* __restrict__ sb,
    float* __restrict__ out, long n8)
{
    __shared__ float s_s[128], s_b[128];
    if (threadIdx.x < 128) {
        s_s[threadIdx.x] = sb[threadIdx.x];
        s_b[threadIdx.x] = sb[128 + threadIdx.x];
    }
    __syncthreads();
    long i = blockIdx.x * 256L + threadIdx.x;
    const long stride = gridDim.x * 256L;
    for (; i < n8; i += stride) {
        const u16x8 v = __builtin_nontemporal_load(((const u16x8*)hb) + i);
        const int c0 = ((int)i & 15) << 3;
        f32x4 o0, o1;
        o0[0] = fmaxf(fmaf(bf2f(v[0]), s_s[c0+0], s_b[c0+0]), 0.f);
        o0[1] = fmaxf(fmaf(bf2f(v[1]), s_s[c0+1], s_b[c0+1]), 0.f);
        o0[2] = fmaxf(fmaf(bf2f(v[2]), s_s[c0+2], s_b[c0+2]), 0.f);
        o0[3] = fmaxf(fmaf(bf2f(v[3]), s_s[c0+3], s_b[c0+3]), 0.f);
        o1[0] = fmaxf(fmaf(bf2f(v[4]), s_s[c0+4], s_b[c0+4]), 0.f);
        o1[1] = fmaxf(fmaf(bf2f(v[5]), s_s[c0+5], s_b[c0+5]), 0.f);
        o1[2] = fmaxf(fmaf(bf2f(v[6]), s_s[c0+6], s_b[c0+6]), 0.f);
        o1[3] = fmaxf(fmaf(bf2f(v[7]), s_s[c0+7], s_b[c0+7]), 0.f);
        __builtin_nontemporal_store(o0, ((f32x4*)out) + i * 2);
        __builtin_nontemporal_store(o1, ((f32x4*)out) + i * 2 + 1);
    }
}

// f32 fallback: in-place on d_out
__global__ __launch_bounds__(256) void bn_relu_kernel(float* __restrict__ h,
                                                      const float* __restrict__ sb, long n4)
{
    __shared__ float s_s[128], s_b[128];
    if (threadIdx.x < 128) {
        s_s[threadIdx.x] = sb[threadIdx.x];
        s_b[threadIdx.x] = sb[128 + threadIdx.x];
    }
    __syncthreads();
    long i = blockIdx.x * 256L + threadIdx.x;
    const long stride = gridDim.x * 256L;
    for (; i < n4; i += stride) {
        f32x4 v = __builtin_nontemporal_load(((const f32x4*)h) + i);
        const int c = ((int)i * 4) & 127;
        v[0] = fmaxf(fmaf(v[0], s_s[c + 0], s_b[c + 0]), 0.f);
        v[1] = fmaxf(fmaf(v[1], s_s[c + 1], s_b[c + 1]), 0.f);
        v[2] = fmaxf(fmaf(v[2], s_s[c + 2], s_b[c + 2]), 0.f);
        v[3] = fmaxf(fmaf(v[3], s_s[c + 3], s_b[c + 3]), 0.f);
        __builtin_nontemporal_store(v, ((f32x4*)h) + i);
    }
}

extern "C" void kernel_launch(void* const* d_in, const int* in_sizes, int n_in,
                              void* d_out, int out_size, void* d_ws, size_t ws_size,
                              hipStream_t stream)
{
    const float* x     = (const float*)d_in[0];
    const int*   nb    = (const int*)d_in[1];
    const float* W     = (const float*)d_in[2];
    const float* gamma = (const float*)d_in[3];
    const float* beta  = (const float*)d_in[4];
    float* out = (float*)d_out;

    const int E = in_sizes[0] / 64;

    // ws layout: Wb 80K | partials 64K | sb 1K | xb (E*128 B) | hb (E*256 B)
    char* ws = (char*)d_ws;
    unsigned short* Wb       = (unsigned short*)ws;
    float*          partials = (float*)(ws + 81920);
    float*          sb       = (float*)(ws + 81920 + 65536);
    unsigned short* xb       = (unsigned short*)(ws + 148480);
    const size_t xb_end = 148480 + (size_t)E * 128;
    unsigned short* hb       = (unsigned short*)(ws + xb_end);
    const bool have_xb = (ws_size >= xb_end);
    const bool have_hb = (ws_size >= xb_end + (size_t)E * 256);

    if (have_xb)
        prep_conv_kernel<<<2048, 256, 0, stream>>>(W, Wb, partials, x, xb, (long)E * 8);
    else
        prep_kernel<<<160, 256, 0, stream>>>(W, Wb, partials);

    const int nblk = (E + 31) / 32;
    void* hdst = have_hb ? (void*)hb : (void*)out;
    if (have_xb && have_hb)
        fused_kernel<true,  true ><<<nblk, 256, 0, stream>>>(x, xb, nb, Wb, hdst, partials, E);
    else if (have_xb)
        fused_kernel<true,  false><<<nblk, 256, 0, stream>>>(x, xb, nb, Wb, hdst, partials, E);
    else if (have_hb)
        fused_kernel<false, true ><<<nblk, 256, 0, stream>>>(x, xb, nb, Wb, hdst, partials, E);
    else
        fused_kernel<false, false><<<nblk, 256, 0, stream>>>(x, xb, nb, Wb, hdst, partials, E);

    finalize_kernel<<<1, 128, 0, stream>>>(partials, gamma, beta, sb, E);

    if (have_hb)
        bn_relu_bf16_kernel<<<2048, 256, 0, stream>>>(hb, sb, out, (long)E * 16);
    else
        bn_relu_kernel<<<2048, 256, 0, stream>>>(out, sb, (long)E * 32);
}